// Round 1
// baseline (268.601 us; speedup 1.0000x reference)
//
#include <hip/hip_runtime.h>
#include <hip/hip_bf16.h>
#include <stdint.h>

// ---------------- types ----------------
typedef __attribute__((ext_vector_type(8))) short   bf16x8;
typedef __attribute__((ext_vector_type(4))) float   f32x4;
typedef __attribute__((ext_vector_type(4))) unsigned short u16x4;

#define N_TOK   4096
#define C_DIM   768
#define NCLU    32

// RNE float->bf16
__device__ __forceinline__ uint16_t f2bf(float f){
  union { float f; unsigned u; } v; v.f = f;
  unsigned r = v.u + 0x7fffu + ((v.u >> 16) & 1u);
  return (uint16_t)(r >> 16);
}

__device__ __forceinline__ void gl2lds16(const void* g, void* l){
  __builtin_amdgcn_global_load_lds(
      (const __attribute__((address_space(1))) unsigned int*)g,
      (__attribute__((address_space(3))) unsigned int*)l, 16, 0, 0);
}

// ---------------- 1) bilinear resize 24x24 -> 32x32, pack v_t[c=h*64+d][n] bf16 ----------------
__global__ __launch_bounds__(256) void resize_k(const float* __restrict__ vext, uint16_t* __restrict__ Vt){
  int id = blockIdx.x * 256 + threadIdx.x;      // 768*4096 total
  int c = id >> 12, n = id & 4095;
  int h = c >> 6,  d = c & 63;
  int b = n >> 10, s = n & 1023, r = s >> 5, w = s & 31;
  float sy = (r + 0.5f) * 0.75f - 0.5f;
  float fy0 = floorf(sy); float fy = sy - fy0; int y0 = (int)fy0;
  int iy0 = y0 < 0 ? 0 : y0;            int iy1 = (y0 + 1 > 23) ? 23 : y0 + 1;
  float sx = (w + 0.5f) * 0.75f - 0.5f;
  float fx0 = floorf(sx); float fx = sx - fx0; int x0 = (int)fx0;
  int ix0 = x0 < 0 ? 0 : x0;            int ix1 = (x0 + 1 > 23) ? 23 : x0 + 1;
  const float* base = vext + ((size_t)(b * 12 + h) * 576) * 64 + d;
  float v00 = base[(iy0 * 24 + ix0) * 64];
  float v01 = base[(iy0 * 24 + ix1) * 64];
  float v10 = base[(iy1 * 24 + ix0) * 64];
  float v11 = base[(iy1 * 24 + ix1) * 64];
  float val = (1.f - fy) * ((1.f - fx) * v00 + fx * v01)
            +        fy  * ((1.f - fx) * v10 + fx * v11);
  Vt[(size_t)c * 4096 + n] = f2bf(val);
}

// ---------------- 2) per-cluster feature sums ----------------
__global__ __launch_bounds__(256) void cluster_sum_k(const float* __restrict__ x, const int* __restrict__ idx,
                                                     float* __restrict__ csum){
  __shared__ int sidx[512];
  const int c = blockIdx.x, chunk = blockIdx.y, jc = blockIdx.z;
  const int tid = threadIdx.x;
  sidx[tid]       = idx[jc * 512 + tid];
  sidx[tid + 256] = idx[jc * 512 + 256 + tid];
  __syncthreads();
  const int ch = chunk * 256 + tid;
  float acc = 0.f;
  const int j0 = jc * 512;
  for (int jj = 0; jj < 512; ++jj)
    if (sidx[jj] == c) acc += x[(size_t)(j0 + jj) * C_DIM + ch];
  atomicAdd(&csum[c * C_DIM + ch], acc);
}

// ---------------- 3) proxy (cluster_sum + distinct-cluster 8-neighbors), l2norm both -> bf16 ----------------
__global__ __launch_bounds__(256) void proxy_key_k(const float* __restrict__ x, const int* __restrict__ idx,
                                                   const float* __restrict__ csum,
                                                   uint16_t* __restrict__ An, uint16_t* __restrict__ Bn){
  __shared__ float red[8];
  const int i = blockIdx.x, tid = threadIdx.x;
  const int ci = idx[i];
  const int b = i >> 10, s = i & 1023, r = s >> 5, w = s & 31;
  const int drs[8] = {-1,-1,-1, 0, 0, 1, 1, 1};
  const int dws[8] = {-1, 0, 1,-1, 1,-1, 0, 1};
  int js[8]; unsigned mask = 0;
  #pragma unroll
  for (int t = 0; t < 8; ++t){
    int rr = r + drs[t], ww = w + dws[t];
    bool ok = ((unsigned)rr < 32u) && ((unsigned)ww < 32u);
    int j = (b << 10) + (rr << 5) + ww;
    js[t] = ok ? j : i;
    if (ok && idx[js[t]] != ci) mask |= (1u << t);
  }
  float xs[3], ps[3]; float ssx = 0.f, ssp = 0.f;
  #pragma unroll
  for (int u = 0; u < 3; ++u){
    int ch = tid + u * 256;
    float xv = x[(size_t)i * C_DIM + ch];
    float pv = csum[ci * C_DIM + ch];
    #pragma unroll
    for (int t = 0; t < 8; ++t)
      if (mask & (1u << t)) pv += x[(size_t)js[t] * C_DIM + ch];
    xs[u] = xv; ps[u] = pv;
    ssx += xv * xv; ssp += pv * pv;
  }
  for (int m = 32; m; m >>= 1){ ssx += __shfl_xor(ssx, m); ssp += __shfl_xor(ssp, m); }
  const int wid = tid >> 6;
  if ((tid & 63) == 0){ red[wid] = ssx; red[4 + wid] = ssp; }
  __syncthreads();
  ssx = red[0] + red[1] + red[2] + red[3];
  ssp = red[4] + red[5] + red[6] + red[7];
  float rnx = 1.f / fmaxf(sqrtf(ssx), 1e-12f);
  float rnp = 1.f / fmaxf(sqrtf(ssp), 1e-12f);
  #pragma unroll
  for (int u = 0; u < 3; ++u){
    int ch = tid + u * 256;
    Bn[(size_t)i * C_DIM + ch] = f2bf(xs[u] * rnx);
    An[(size_t)i * C_DIM + ch] = f2bf(ps[u] * rnp);
  }
}

// ---------------- 4/7) bf16 MFMA GEMM, C = A * B^T (A[M,K], B[N,K] row-major) ----------------
// MODE 0: store fp32 C into Cout[row*4096+col]   (S matrix)
// MODE 1: atomicAdd( out[(row&1023)*3072 + (row>>10)*768 + col], C*rden[row] )  (K-split over gridDim.z)
template<int MODE>
__global__ __launch_bounds__(256) void gemm_bt_k(const uint16_t* __restrict__ A, const uint16_t* __restrict__ B,
                                                 int ldA, int ldB, int K,
                                                 float* __restrict__ Cout,
                                                 const float* __restrict__ rden,
                                                 float* __restrict__ Obuf){
  __shared__ __align__(16) char smem[32768];       // A tile 16KB @0, B tile 16KB @16384
  const int tid  = threadIdx.x;
  const int lane = tid & 63, wid = tid >> 6;
  const int q = lane >> 4, l16 = lane & 15;
  const int wrow = wid & 1, wcol = wid >> 1;
  const int i0 = blockIdx.y * 128;
  const int n0 = blockIdx.x * 128;

  f32x4 acc[4][4] = {};

  const int KT  = K >> 6;
  const int per = KT / gridDim.z;
  const int kt0 = blockIdx.z * per;

  for (int kt = kt0; kt < kt0 + per; ++kt){
    const int k0 = kt << 6;
    #pragma unroll
    for (int t = 0; t < 4; ++t){
      int p   = t * 256 + tid;
      int row = p >> 3, kc = p & 7;
      int kcs = kc ^ (row & 7);                    // XOR swizzle on the GLOBAL side
      gl2lds16(A + (size_t)(i0 + row) * ldA + k0 + kcs * 8, smem + p * 16);
      gl2lds16(B + (size_t)(n0 + row) * ldB + k0 + kcs * 8, smem + 16384 + p * 16);
    }
    __syncthreads();                               // drains vmcnt
    #pragma unroll
    for (int ks = 0; ks < 2; ++ks){
      bf16x8 af[4], bfr[4];
      #pragma unroll
      for (int mt = 0; mt < 4; ++mt){
        int row = wrow * 64 + mt * 16 + l16;
        int ck  = (ks * 4 + q) ^ (row & 7);
        af[mt] = *(const bf16x8*)(smem + row * 128 + ck * 16);
      }
      #pragma unroll
      for (int nt = 0; nt < 4; ++nt){
        int row = wcol * 64 + nt * 16 + l16;
        int ck  = (ks * 4 + q) ^ (row & 7);
        bfr[nt] = *(const bf16x8*)(smem + 16384 + row * 128 + ck * 16);
      }
      #pragma unroll
      for (int mt = 0; mt < 4; ++mt)
        #pragma unroll
        for (int nt = 0; nt < 4; ++nt)
          acc[mt][nt] = __builtin_amdgcn_mfma_f32_16x16x32_bf16(af[mt], bfr[nt], acc[mt][nt], 0, 0, 0);
    }
    __syncthreads();
  }

  #pragma unroll
  for (int mt = 0; mt < 4; ++mt){
    #pragma unroll
    for (int r = 0; r < 4; ++r){
      int row = i0 + wrow * 64 + mt * 16 + q * 4 + r;   // C/D: col=lane&15, row=(lane>>4)*4+reg
      float rd = (MODE == 1) ? rden[row] : 0.f;
      #pragma unroll
      for (int nt = 0; nt < 4; ++nt){
        int col = n0 + wcol * 64 + nt * 16 + l16;
        float v = acc[mt][nt][r];
        if (MODE == 0)
          Cout[(size_t)row * 4096 + col] = v;
        else
          atomicAdd(&Obuf[(size_t)(row & 1023) * 3072 + (row >> 10) * 768 + col], v * rd);
      }
    }
  }
}

// ---------------- 5/6) row stats + cut + exp -> P bf16, 1/denom ----------------
__global__ __launch_bounds__(256) void rowsoftmax_k(const float* __restrict__ S, uint16_t* __restrict__ P,
                                                    float* __restrict__ rden){
  __shared__ float red[8];
  const int row = blockIdx.x, tid = threadIdx.x;
  const float4* Sr = (const float4*)(S + (size_t)row * 4096);
  float4 v[4];
  float mx = -3.4e38f, sm = 0.f;
  #pragma unroll
  for (int j = 0; j < 4; ++j){
    v[j] = Sr[j * 256 + tid];
    mx = fmaxf(mx, fmaxf(fmaxf(v[j].x, v[j].y), fmaxf(v[j].z, v[j].w)));
    sm += v[j].x + v[j].y + v[j].z + v[j].w;
  }
  for (int m = 32; m; m >>= 1){ mx = fmaxf(mx, __shfl_xor(mx, m)); sm += __shfl_xor(sm, m); }
  const int wid = tid >> 6;
  if ((tid & 63) == 0){ red[wid] = mx; red[4 + wid] = sm; }
  __syncthreads();
  mx = fmaxf(fmaxf(red[0], red[1]), fmaxf(red[2], red[3]));
  sm = red[4] + red[5] + red[6] + red[7];

  float bmu  = 1.2f * fmaxf(sm * (1.f / 4096.f), 0.f);
  float amax = 3.0f * (mx - bmu);                 // identical expression to per-element 'a' below
  float cut  = fminf(amax, 0.1f);

  float den = 0.f; uint16_t pv[16];
  #pragma unroll
  for (int j = 0; j < 4; ++j){
    float pf[4] = { v[j].x, v[j].y, v[j].z, v[j].w };
    #pragma unroll
    for (int e = 0; e < 4; ++e){
      float a  = 3.0f * (pf[e] - bmu);
      float ev = (a >= cut) ? __expf((a - amax) * (1.f / 0.07f)) : 0.f;
      den += ev;
      pv[j * 4 + e] = f2bf(ev);
    }
  }
  for (int m = 32; m; m >>= 1) den += __shfl_xor(den, m);
  __syncthreads();
  if ((tid & 63) == 0) red[wid] = den;
  __syncthreads();
  den = red[0] + red[1] + red[2] + red[3];
  if (tid == 0) rden[row] = 1.f / den;            // den >= 1 (argmax always kept)

  u16x4* Pr = (u16x4*)(P + (size_t)row * 4096);
  #pragma unroll
  for (int j = 0; j < 4; ++j){
    u16x4 o = { pv[j*4+0], pv[j*4+1], pv[j*4+2], pv[j*4+3] };
    Pr[j * 256 + tid] = o;
  }
}

// ---------------- launcher ----------------
extern "C" void kernel_launch(void* const* d_in, const int* in_sizes, int n_in,
                              void* d_out, int out_size, void* d_ws, size_t ws_size,
                              hipStream_t stream){
  (void)in_sizes; (void)n_in; (void)out_size; (void)ws_size;
  const float* ex   = (const float*)d_in[0];   // [4,1024,768] -> x[4096,768]
  const float* vext = (const float*)d_in[1];   // [48,24,24,64]
  const int*   idx  = (const int*)d_in[2];     // [4096]
  float* out = (float*)d_out;                  // [1024,4,768] fp32
  char* ws = (char*)d_ws;

  // ws layout (total ~119.7 MB)
  float*    Sbuf = (float*)(ws);                        // 67108864 B
  uint16_t* P    = (uint16_t*)(ws + 67108864);          // 33554432 B
  uint16_t* An   = (uint16_t*)(ws + 100663296);         //  6291456 B (proxyn bf16)
  uint16_t* Bn   = (uint16_t*)(ws + 106954752);         //  6291456 B (keyn  bf16)
  uint16_t* Vt   = (uint16_t*)(ws + 113246208);         //  6291456 B (v_t[768][4096] bf16)
  float*    csum = (float*)(ws + 119537664);            //    98304 B
  float*    rden = (float*)(ws + 119635968);            //    16384 B

  hipMemsetAsync(csum, 0, NCLU * C_DIM * sizeof(float), stream);
  hipMemsetAsync(out, 0, (size_t)1024 * 4 * 768 * sizeof(float), stream);  // GEMM2 K-split accumulates

  resize_k<<<12288, 256, 0, stream>>>(vext, Vt);
  cluster_sum_k<<<dim3(NCLU, 3, 8), 256, 0, stream>>>(ex, idx, csum);
  proxy_key_k<<<N_TOK, 256, 0, stream>>>(ex, idx, csum, An, Bn);
  // S = proxyn @ keyn^T   [4096 x 4096], K=768
  gemm_bt_k<0><<<dim3(32, 32, 1), 256, 0, stream>>>(An, Bn, 768, 768, 768, Sbuf, nullptr, nullptr);
  rowsoftmax_k<<<N_TOK, 256, 0, stream>>>(Sbuf, P, rden);
  // out = softmax(S) @ v   [4096 x 768], K=4096, K-split x4
  gemm_bt_k<1><<<dim3(6, 32, 4), 256, 0, stream>>>(P, Vt, 4096, 4096, 4096, nullptr, rden, out);
}

// Round 2
// 253.558 us; speedup vs baseline: 1.0593x; 1.0593x over previous
//
#include <hip/hip_runtime.h>
#include <hip/hip_bf16.h>
#include <stdint.h>

// ---------------- types ----------------
typedef __attribute__((ext_vector_type(8))) short    bf16x8;
typedef __attribute__((ext_vector_type(4))) float    f32x4;
typedef __attribute__((ext_vector_type(8))) unsigned short u16x8;
typedef __attribute__((ext_vector_type(8))) _Float16 f16x8;

#define N_TOK   4096
#define C_DIM   768
#define NCLU    32

// RNE float->bf16
__device__ __forceinline__ uint16_t f2bf(float f){
  union { float f; unsigned u; } v; v.f = f;
  unsigned r = v.u + 0x7fffu + ((v.u >> 16) & 1u);
  return (uint16_t)(r >> 16);
}

__device__ __forceinline__ void gl2lds16(const void* g, void* l){
  __builtin_amdgcn_global_load_lds(
      (const __attribute__((address_space(1))) unsigned int*)g,
      (__attribute__((address_space(3))) unsigned int*)l, 16, 0, 0);
}

// ---------------- 1) bilinear resize 24x24 -> 32x32, pack v_t[c=h*64+d][n] bf16 ----------------
__global__ __launch_bounds__(256) void resize_k(const float* __restrict__ vext, uint16_t* __restrict__ Vt){
  int id = blockIdx.x * 256 + threadIdx.x;      // 768*4096 total
  int c = id >> 12, n = id & 4095;
  int h = c >> 6,  d = c & 63;
  int b = n >> 10, s = n & 1023, r = s >> 5, w = s & 31;
  float sy = (r + 0.5f) * 0.75f - 0.5f;
  float fy0 = floorf(sy); float fy = sy - fy0; int y0 = (int)fy0;
  int iy0 = y0 < 0 ? 0 : y0;            int iy1 = (y0 + 1 > 23) ? 23 : y0 + 1;
  float sx = (w + 0.5f) * 0.75f - 0.5f;
  float fx0 = floorf(sx); float fx = sx - fx0; int x0 = (int)fx0;
  int ix0 = x0 < 0 ? 0 : x0;            int ix1 = (x0 + 1 > 23) ? 23 : x0 + 1;
  const float* base = vext + ((size_t)(b * 12 + h) * 576) * 64 + d;
  float v00 = base[(iy0 * 24 + ix0) * 64];
  float v01 = base[(iy0 * 24 + ix1) * 64];
  float v10 = base[(iy1 * 24 + ix0) * 64];
  float v11 = base[(iy1 * 24 + ix1) * 64];
  float val = (1.f - fy) * ((1.f - fx) * v00 + fx * v01)
            +        fy  * ((1.f - fx) * v10 + fx * v11);
  Vt[(size_t)c * 4096 + n] = f2bf(val);
}

// ---------------- 2) per-cluster feature sums ----------------
__global__ __launch_bounds__(256) void cluster_sum_k(const float* __restrict__ x, const int* __restrict__ idx,
                                                     float* __restrict__ csum){
  __shared__ int sidx[512];
  const int c = blockIdx.x, chunk = blockIdx.y, jc = blockIdx.z;
  const int tid = threadIdx.x;
  sidx[tid]       = idx[jc * 512 + tid];
  sidx[tid + 256] = idx[jc * 512 + 256 + tid];
  __syncthreads();
  const int ch = chunk * 256 + tid;
  float acc = 0.f;
  const int j0 = jc * 512;
  for (int jj = 0; jj < 512; ++jj)
    if (sidx[jj] == c) acc += x[(size_t)(j0 + jj) * C_DIM + ch];
  atomicAdd(&csum[c * C_DIM + ch], acc);
}

// ---------------- 3) proxy (cluster_sum + distinct-cluster 8-neighbors), l2norm both -> bf16 ----------------
__global__ __launch_bounds__(256) void proxy_key_k(const float* __restrict__ x, const int* __restrict__ idx,
                                                   const float* __restrict__ csum,
                                                   uint16_t* __restrict__ An, uint16_t* __restrict__ Bn){
  __shared__ float red[8];
  const int i = blockIdx.x, tid = threadIdx.x;
  const int ci = idx[i];
  const int b = i >> 10, s = i & 1023, r = s >> 5, w = s & 31;
  const int drs[8] = {-1,-1,-1, 0, 0, 1, 1, 1};
  const int dws[8] = {-1, 0, 1,-1, 1,-1, 0, 1};
  int js[8]; unsigned mask = 0;
  #pragma unroll
  for (int t = 0; t < 8; ++t){
    int rr = r + drs[t], ww = w + dws[t];
    bool ok = ((unsigned)rr < 32u) && ((unsigned)ww < 32u);
    int j = (b << 10) + (rr << 5) + ww;
    js[t] = ok ? j : i;
    if (ok && idx[js[t]] != ci) mask |= (1u << t);
  }
  float xs[3], ps[3]; float ssx = 0.f, ssp = 0.f;
  #pragma unroll
  for (int u = 0; u < 3; ++u){
    int ch = tid + u * 256;
    float xv = x[(size_t)i * C_DIM + ch];
    float pv = csum[ci * C_DIM + ch];
    #pragma unroll
    for (int t = 0; t < 8; ++t)
      if (mask & (1u << t)) pv += x[(size_t)js[t] * C_DIM + ch];
    xs[u] = xv; ps[u] = pv;
    ssx += xv * xv; ssp += pv * pv;
  }
  for (int m = 32; m; m >>= 1){ ssx += __shfl_xor(ssx, m); ssp += __shfl_xor(ssp, m); }
  const int wid = tid >> 6;
  if ((tid & 63) == 0){ red[wid] = ssx; red[4 + wid] = ssp; }
  __syncthreads();
  ssx = red[0] + red[1] + red[2] + red[3];
  ssp = red[4] + red[5] + red[6] + red[7];
  float rnx = 1.f / fmaxf(sqrtf(ssx), 1e-12f);
  float rnp = 1.f / fmaxf(sqrtf(ssp), 1e-12f);
  #pragma unroll
  for (int u = 0; u < 3; ++u){
    int ch = tid + u * 256;
    Bn[(size_t)i * C_DIM + ch] = f2bf(xs[u] * rnx);
    An[(size_t)i * C_DIM + ch] = f2bf(ps[u] * rnp);
  }
}

// ---------------- 4/7) bf16 MFMA GEMM, C = A * B^T (A[M,K], B[N,K] row-major) ----------------
// 1D grid with XCD-aware tile swizzle (block g runs on XCD g%8).
// MODE 0: grid 1024 = 32m x 32n, K=768.  Each XCD owns an 8m x 16n region (~4.7MB working set).
//         Stores fp16 S.
// MODE 1: grid 768 = 32m x 6n x 4z (K-split), K=4096. Each XCD owns 16m x 6n x 1z
//         (A 4MB + B 1.5MB working set). atomicAdd(out * rden[row]).
template<int MODE>
__global__ __launch_bounds__(256) void gemm_bt_k(const uint16_t* __restrict__ A, const uint16_t* __restrict__ B,
                                                 int ldA, int ldB, int K,
                                                 _Float16* __restrict__ Sout,
                                                 const float* __restrict__ rden,
                                                 float* __restrict__ Obuf){
  __shared__ __align__(16) char smem[32768];       // A tile 16KB @0, B tile 16KB @16384
  const int tid  = threadIdx.x;
  const int lane = tid & 63, wid = tid >> 6;
  const int q = lane >> 4, l16 = lane & 15;
  const int wrow = wid & 1, wcol = wid >> 1;

  // ---- XCD swizzle ----
  const int g = blockIdx.x;
  const int xcd = g & 7;
  const int j   = g >> 3;
  int i0, n0, kt0, per;
  const int KT = K >> 6;
  if (MODE == 0){
    int sq = j >> 4;                                  // 0..7: 2x4 grid of 4x4 sub-blocks
    int mi = ((sq >> 2) << 2) + ((j >> 2) & 3);       // 0..7
    int ni = ((sq & 3) << 2) + (j & 3);               // 0..15
    i0 = (((xcd >> 1) << 3) + mi) * 128;              // m in [0,32)
    n0 = (((xcd & 1) << 4) + ni) * 128;               // n in [0,32)
    kt0 = 0; per = KT;
  } else {
    int z = xcd >> 1;                                 // 0..3
    i0 = (((xcd & 1) << 4) + j / 6) * 128;            // m in [0,32)
    n0 = (j % 6) * 128;                               // n in [0,6)
    per = KT >> 2; kt0 = z * per;
  }

  f32x4 acc[4][4] = {};

  for (int kt = kt0; kt < kt0 + per; ++kt){
    const int k0 = kt << 6;
    #pragma unroll
    for (int t = 0; t < 4; ++t){
      int p   = t * 256 + tid;
      int row = p >> 3, kc = p & 7;
      int kcs = kc ^ (row & 7);                    // XOR swizzle on the GLOBAL side
      gl2lds16(A + (size_t)(i0 + row) * ldA + k0 + kcs * 8, smem + p * 16);
      gl2lds16(B + (size_t)(n0 + row) * ldB + k0 + kcs * 8, smem + 16384 + p * 16);
    }
    __syncthreads();                               // drains vmcnt
    #pragma unroll
    for (int ks = 0; ks < 2; ++ks){
      bf16x8 af[4], bfr[4];
      #pragma unroll
      for (int mt = 0; mt < 4; ++mt){
        int row = wrow * 64 + mt * 16 + l16;
        int ck  = (ks * 4 + q) ^ (row & 7);
        af[mt] = *(const bf16x8*)(smem + row * 128 + ck * 16);
      }
      #pragma unroll
      for (int nt = 0; nt < 4; ++nt){
        int row = wcol * 64 + nt * 16 + l16;
        int ck  = (ks * 4 + q) ^ (row & 7);
        bfr[nt] = *(const bf16x8*)(smem + 16384 + row * 128 + ck * 16);
      }
      #pragma unroll
      for (int mt = 0; mt < 4; ++mt)
        #pragma unroll
        for (int nt = 0; nt < 4; ++nt)
          acc[mt][nt] = __builtin_amdgcn_mfma_f32_16x16x32_bf16(af[mt], bfr[nt], acc[mt][nt], 0, 0, 0);
    }
    __syncthreads();
  }

  #pragma unroll
  for (int mt = 0; mt < 4; ++mt){
    #pragma unroll
    for (int r = 0; r < 4; ++r){
      int row = i0 + wrow * 64 + mt * 16 + q * 4 + r;   // C/D: col=lane&15, row=(lane>>4)*4+reg
      float rd = (MODE == 1) ? rden[row] : 0.f;
      #pragma unroll
      for (int nt = 0; nt < 4; ++nt){
        int col = n0 + wcol * 64 + nt * 16 + l16;
        float v = acc[mt][nt][r];
        if (MODE == 0)
          Sout[(size_t)row * 4096 + col] = (_Float16)v;
        else
          atomicAdd(&Obuf[(size_t)(row & 1023) * 3072 + (row >> 10) * 768 + col], v * rd);
      }
    }
  }
}

// ---------------- 5/6) row stats + cut + exp -> P bf16, 1/denom ----------------
__global__ __launch_bounds__(256) void rowsoftmax_k(const _Float16* __restrict__ S, uint16_t* __restrict__ P,
                                                    float* __restrict__ rden){
  __shared__ float red[8];
  const int row = blockIdx.x, tid = threadIdx.x;
  const f16x8* Sr = (const f16x8*)(S + (size_t)row * 4096);
  f16x8 h0 = Sr[tid], h1 = Sr[256 + tid];
  float v[16];
  float mx = -3.4e38f, sm = 0.f;
  #pragma unroll
  for (int e = 0; e < 8; ++e){ v[e] = (float)h0[e]; v[8 + e] = (float)h1[e]; }
  #pragma unroll
  for (int e = 0; e < 16; ++e){ mx = fmaxf(mx, v[e]); sm += v[e]; }
  for (int m = 32; m; m >>= 1){ mx = fmaxf(mx, __shfl_xor(mx, m)); sm += __shfl_xor(sm, m); }
  const int wid = tid >> 6;
  if ((tid & 63) == 0){ red[wid] = mx; red[4 + wid] = sm; }
  __syncthreads();
  mx = fmaxf(fmaxf(red[0], red[1]), fmaxf(red[2], red[3]));
  sm = red[4] + red[5] + red[6] + red[7];

  float bmu  = 1.2f * fmaxf(sm * (1.f / 4096.f), 0.f);
  float amax = 3.0f * (mx - bmu);                 // identical expression to per-element 'a' below
  float cut  = fminf(amax, 0.1f);

  float den = 0.f; uint16_t pv[16];
  #pragma unroll
  for (int e = 0; e < 16; ++e){
    float a  = 3.0f * (v[e] - bmu);
    float ev = (a >= cut) ? __expf((a - amax) * (1.f / 0.07f)) : 0.f;
    den += ev;
    pv[e] = f2bf(ev);
  }
  for (int m = 32; m; m >>= 1) den += __shfl_xor(den, m);
  __syncthreads();
  if ((tid & 63) == 0) red[wid] = den;
  __syncthreads();
  den = red[0] + red[1] + red[2] + red[3];
  if (tid == 0) rden[row] = 1.f / den;            // den >= 1 (argmax always kept)

  u16x8* Pr = (u16x8*)(P + (size_t)row * 4096);
  u16x8 o0, o1;
  #pragma unroll
  for (int e = 0; e < 8; ++e){ o0[e] = pv[e]; o1[e] = pv[8 + e]; }
  Pr[tid] = o0; Pr[256 + tid] = o1;
}

// ---------------- launcher ----------------
extern "C" void kernel_launch(void* const* d_in, const int* in_sizes, int n_in,
                              void* d_out, int out_size, void* d_ws, size_t ws_size,
                              hipStream_t stream){
  (void)in_sizes; (void)n_in; (void)out_size; (void)ws_size;
  const float* ex   = (const float*)d_in[0];   // [4,1024,768] -> x[4096,768]
  const float* vext = (const float*)d_in[1];   // [48,24,24,64]
  const int*   idx  = (const int*)d_in[2];     // [4096]
  float* out = (float*)d_out;                  // [1024,4,768] fp32
  char* ws = (char*)d_ws;

  // ws layout (total ~86.1 MB)
  _Float16* S16 = (_Float16*)(ws);                      // 33554432 B
  uint16_t* P    = (uint16_t*)(ws + 33554432);          // 33554432 B
  uint16_t* An   = (uint16_t*)(ws + 67108864);          //  6291456 B (proxyn bf16)
  uint16_t* Bn   = (uint16_t*)(ws + 73400320);          //  6291456 B (keyn  bf16)
  uint16_t* Vt   = (uint16_t*)(ws + 79691776);          //  6291456 B (v_t[768][4096] bf16)
  float*    csum = (float*)(ws + 85983232);             //    98304 B
  float*    rden = (float*)(ws + 86081536);             //    16384 B

  hipMemsetAsync(csum, 0, NCLU * C_DIM * sizeof(float), stream);
  hipMemsetAsync(out, 0, (size_t)1024 * 4 * 768 * sizeof(float), stream);  // GEMM2 K-split accumulates

  resize_k<<<12288, 256, 0, stream>>>(vext, Vt);
  cluster_sum_k<<<dim3(NCLU, 3, 8), 256, 0, stream>>>(ex, idx, csum);
  proxy_key_k<<<N_TOK, 256, 0, stream>>>(ex, idx, csum, An, Bn);
  // S = proxyn @ keyn^T   [4096 x 4096], K=768, fp16 out, XCD-swizzled
  gemm_bt_k<0><<<1024, 256, 0, stream>>>(An, Bn, 768, 768, 768, S16, nullptr, nullptr);
  rowsoftmax_k<<<N_TOK, 256, 0, stream>>>(S16, P, rden);
  // out = softmax(S) @ v   [4096 x 768], K=4096, K-split x4, XCD-swizzled
  gemm_bt_k<1><<<768, 256, 0, stream>>>(P, Vt, 4096, 4096, 4096, nullptr, rden, out);
}

// Round 3
// 224.912 us; speedup vs baseline: 1.1943x; 1.1274x over previous
//
#include <hip/hip_runtime.h>
#include <hip/hip_bf16.h>
#include <stdint.h>

// ---------------- types ----------------
typedef __attribute__((ext_vector_type(8))) short    bf16x8;
typedef __attribute__((ext_vector_type(4))) float    f32x4;
typedef __attribute__((ext_vector_type(8))) unsigned short u16x8;
typedef __attribute__((ext_vector_type(8))) _Float16 f16x8;

#define N_TOK   4096
#define C_DIM   768
#define NCLU    32

// RNE float->bf16
__device__ __forceinline__ uint16_t f2bf(float f){
  union { float f; unsigned u; } v; v.f = f;
  unsigned r = v.u + 0x7fffu + ((v.u >> 16) & 1u);
  return (uint16_t)(r >> 16);
}

__device__ __forceinline__ void gl2lds16(const void* g, void* l){
  __builtin_amdgcn_global_load_lds(
      (const __attribute__((address_space(1))) unsigned int*)g,
      (__attribute__((address_space(3))) unsigned int*)l, 16, 0, 0);
}

// ---------------- 1) bilinear resize 24x24 -> 32x32 with LDS transpose ----------------
// grid = (48 bh) x (32 y); block 256. Phase 1: d-major compute (coalesced 256B taps)
// into LDS[64][33]; phase 2: x-major coalesced bf16 writes to Vt[c=h*64+d][n].
__global__ __launch_bounds__(256) void resize_k(const float* __restrict__ vext, uint16_t* __restrict__ Vt){
  __shared__ float ld[64 * 33];
  const int bh = blockIdx.x, y = blockIdx.y;
  const int b = bh / 12, h = bh % 12;
  const float* base = vext + (size_t)bh * 576 * 64;

  float sy = (y + 0.5f) * 0.75f - 0.5f;
  float fy0 = floorf(sy); float fy = sy - fy0; int y0 = (int)fy0;
  int iy0 = y0 < 0 ? 0 : y0;  int iy1 = (y0 + 1 > 23) ? 23 : y0 + 1;

  const int t = threadIdx.x;
  const int d = t & 63, xg = t >> 6;          // 64 d-lanes x 4 x-groups
  #pragma unroll
  for (int j = 0; j < 8; ++j){
    int x = xg + 4 * j;                       // x in [0,32)
    float sx = (x + 0.5f) * 0.75f - 0.5f;
    float fx0 = floorf(sx); float fx = sx - fx0; int x0 = (int)fx0;
    int ix0 = x0 < 0 ? 0 : x0;  int ix1 = (x0 + 1 > 23) ? 23 : x0 + 1;
    float v00 = base[(iy0 * 24 + ix0) * 64 + d];
    float v01 = base[(iy0 * 24 + ix1) * 64 + d];
    float v10 = base[(iy1 * 24 + ix0) * 64 + d];
    float v11 = base[(iy1 * 24 + ix1) * 64 + d];
    ld[d * 33 + x] = (1.f - fy) * ((1.f - fx) * v00 + fx * v01)
                   +        fy  * ((1.f - fx) * v10 + fx * v11);
  }
  __syncthreads();
  const int x = t & 31, dg = t >> 5;          // 32 x-lanes x 8 d-groups
  const int n = b * 1024 + y * 32 + x;
  #pragma unroll
  for (int j = 0; j < 8; ++j){
    int d2 = dg * 8 + j;
    Vt[(size_t)(h * 64 + d2) * 4096 + n] = f2bf(ld[d2 * 33 + x]);
  }
}

// ---------------- 2a) counting sort of cluster indices (1 block) ----------------
__global__ __launch_bounds__(256) void sort_k(const int* __restrict__ idx, int* __restrict__ order,
                                              int* __restrict__ cbase){
  __shared__ int hist[NCLU], base[NCLU], cur[NCLU];
  const int tid = threadIdx.x;
  if (tid < NCLU) hist[tid] = 0;
  __syncthreads();
  for (int i = tid; i < N_TOK; i += 256) atomicAdd(&hist[idx[i]], 1);
  __syncthreads();
  if (tid == 0){
    int s = 0;
    for (int c = 0; c < NCLU; ++c){ base[c] = s; cur[c] = s; s += hist[c]; }
  }
  __syncthreads();
  for (int i = tid; i < N_TOK; i += 256){
    int p = atomicAdd(&cur[idx[i]], 1);
    order[p] = i;
  }
  if (tid < NCLU){ cbase[tid] = base[tid]; cbase[NCLU + tid] = hist[tid]; }
}

// ---------------- 2b) per-cluster feature sums: read x exactly once ----------------
__global__ __launch_bounds__(256) void csum_k(const float* __restrict__ x, const int* __restrict__ order,
                                              const int* __restrict__ cbase, float* __restrict__ csum){
  const int c = blockIdx.x;
  const int ch = blockIdx.y * 256 + threadIdx.x;
  const int b0 = cbase[c], n = cbase[NCLU + c];
  float acc = 0.f;
  int k = 0;
  for (; k + 4 <= n; k += 4){
    int r0 = order[b0 + k], r1 = order[b0 + k + 1], r2 = order[b0 + k + 2], r3 = order[b0 + k + 3];
    acc += x[(size_t)r0 * C_DIM + ch] + x[(size_t)r1 * C_DIM + ch]
         + x[(size_t)r2 * C_DIM + ch] + x[(size_t)r3 * C_DIM + ch];
  }
  for (; k < n; ++k) acc += x[(size_t)order[b0 + k] * C_DIM + ch];
  csum[c * C_DIM + ch] = acc;
}

// ---------------- 3) proxy (cluster_sum + distinct-cluster 8-neighbors), l2norm both -> bf16 ----------------
__global__ __launch_bounds__(256) void proxy_key_k(const float* __restrict__ x, const int* __restrict__ idx,
                                                   const float* __restrict__ csum,
                                                   uint16_t* __restrict__ An, uint16_t* __restrict__ Bn){
  __shared__ float red[8];
  const int i = blockIdx.x, tid = threadIdx.x;
  const int ci = idx[i];
  const int b = i >> 10, s = i & 1023, r = s >> 5, w = s & 31;
  const int drs[8] = {-1,-1,-1, 0, 0, 1, 1, 1};
  const int dws[8] = {-1, 0, 1,-1, 1,-1, 0, 1};
  int js[8]; unsigned mask = 0;
  #pragma unroll
  for (int t = 0; t < 8; ++t){
    int rr = r + drs[t], ww = w + dws[t];
    bool ok = ((unsigned)rr < 32u) && ((unsigned)ww < 32u);
    int j = (b << 10) + (rr << 5) + ww;
    js[t] = ok ? j : i;
    if (ok && idx[js[t]] != ci) mask |= (1u << t);
  }
  float xs[3], ps[3]; float ssx = 0.f, ssp = 0.f;
  #pragma unroll
  for (int u = 0; u < 3; ++u){
    int ch = tid + u * 256;
    float xv = x[(size_t)i * C_DIM + ch];
    float pv = csum[ci * C_DIM + ch];
    #pragma unroll
    for (int t = 0; t < 8; ++t)
      if (mask & (1u << t)) pv += x[(size_t)js[t] * C_DIM + ch];
    xs[u] = xv; ps[u] = pv;
    ssx += xv * xv; ssp += pv * pv;
  }
  for (int m = 32; m; m >>= 1){ ssx += __shfl_xor(ssx, m); ssp += __shfl_xor(ssp, m); }
  const int wid = tid >> 6;
  if ((tid & 63) == 0){ red[wid] = ssx; red[4 + wid] = ssp; }
  __syncthreads();
  ssx = red[0] + red[1] + red[2] + red[3];
  ssp = red[4] + red[5] + red[6] + red[7];
  float rnx = 1.f / fmaxf(sqrtf(ssx), 1e-12f);
  float rnp = 1.f / fmaxf(sqrtf(ssp), 1e-12f);
  #pragma unroll
  for (int u = 0; u < 3; ++u){
    int ch = tid + u * 256;
    Bn[(size_t)i * C_DIM + ch] = f2bf(xs[u] * rnx);
    An[(size_t)i * C_DIM + ch] = f2bf(ps[u] * rnp);
  }
}

// ---------------- 4/7) bf16 MFMA GEMM, C = A * B^T (A[M,K], B[N,K] row-major) ----------------
// 1D grid with XCD-aware tile swizzle (block g runs on XCD g%8).
// MODE 0: grid 1024 = 32m x 32n, K=768.  Each XCD owns an 8m x 16n region. Stores fp16 S.
// MODE 1: grid 768 = 32m x 6n x 4z (K-split), K=4096. Plain fp32 stores to per-z
//         partial buffers Obuf[z][4096][768] (no atomics).
template<int MODE>
__global__ __launch_bounds__(256) void gemm_bt_k(const uint16_t* __restrict__ A, const uint16_t* __restrict__ B,
                                                 int ldA, int ldB, int K,
                                                 _Float16* __restrict__ Sout,
                                                 float* __restrict__ Obuf){
  __shared__ __align__(16) char smem[32768];       // A tile 16KB @0, B tile 16KB @16384
  const int tid  = threadIdx.x;
  const int lane = tid & 63, wid = tid >> 6;
  const int q = lane >> 4, l16 = lane & 15;
  const int wrow = wid & 1, wcol = wid >> 1;

  // ---- XCD swizzle ----
  const int g = blockIdx.x;
  const int xcd = g & 7;
  const int j   = g >> 3;
  int i0, n0, kt0, per, z = 0;
  const int KT = K >> 6;
  if (MODE == 0){
    int sq = j >> 4;                                  // 0..7: 2x4 grid of 4x4 sub-blocks
    int mi = ((sq >> 2) << 2) + ((j >> 2) & 3);       // 0..7
    int ni = ((sq & 3) << 2) + (j & 3);               // 0..15
    i0 = (((xcd >> 1) << 3) + mi) * 128;              // m in [0,32)
    n0 = (((xcd & 1) << 4) + ni) * 128;               // n in [0,32)
    kt0 = 0; per = KT;
  } else {
    z  = xcd >> 1;                                    // 0..3
    i0 = (((xcd & 1) << 4) + j / 6) * 128;            // m in [0,32)
    n0 = (j % 6) * 128;                               // n in [0,6)
    per = KT >> 2; kt0 = z * per;
  }

  f32x4 acc[4][4] = {};

  for (int kt = kt0; kt < kt0 + per; ++kt){
    const int k0 = kt << 6;
    #pragma unroll
    for (int t = 0; t < 4; ++t){
      int p   = t * 256 + tid;
      int row = p >> 3, kc = p & 7;
      int kcs = kc ^ (row & 7);                    // XOR swizzle on the GLOBAL side
      gl2lds16(A + (size_t)(i0 + row) * ldA + k0 + kcs * 8, smem + p * 16);
      gl2lds16(B + (size_t)(n0 + row) * ldB + k0 + kcs * 8, smem + 16384 + p * 16);
    }
    __syncthreads();                               // drains vmcnt
    #pragma unroll
    for (int ks = 0; ks < 2; ++ks){
      bf16x8 af[4], bfr[4];
      #pragma unroll
      for (int mt = 0; mt < 4; ++mt){
        int row = wrow * 64 + mt * 16 + l16;
        int ck  = (ks * 4 + q) ^ (row & 7);
        af[mt] = *(const bf16x8*)(smem + row * 128 + ck * 16);
      }
      #pragma unroll
      for (int nt = 0; nt < 4; ++nt){
        int row = wcol * 64 + nt * 16 + l16;
        int ck  = (ks * 4 + q) ^ (row & 7);
        bfr[nt] = *(const bf16x8*)(smem + 16384 + row * 128 + ck * 16);
      }
      #pragma unroll
      for (int mt = 0; mt < 4; ++mt)
        #pragma unroll
        for (int nt = 0; nt < 4; ++nt)
          acc[mt][nt] = __builtin_amdgcn_mfma_f32_16x16x32_bf16(af[mt], bfr[nt], acc[mt][nt], 0, 0, 0);
    }
    __syncthreads();
  }

  float* Pz = (MODE == 1) ? (Obuf + (size_t)z * N_TOK * C_DIM) : nullptr;
  #pragma unroll
  for (int mt = 0; mt < 4; ++mt){
    #pragma unroll
    for (int r = 0; r < 4; ++r){
      int row = i0 + wrow * 64 + mt * 16 + q * 4 + r;   // C/D: col=lane&15, row=(lane>>4)*4+reg
      #pragma unroll
      for (int nt = 0; nt < 4; ++nt){
        int col = n0 + wcol * 64 + nt * 16 + l16;
        float v = acc[mt][nt][r];
        if (MODE == 0)
          Sout[(size_t)row * 4096 + col] = (_Float16)v;
        else
          Pz[(size_t)row * C_DIM + col] = v;
      }
    }
  }
}

// ---------------- 5/6) row stats + cut + exp -> P bf16, 1/denom ----------------
__global__ __launch_bounds__(256) void rowsoftmax_k(const _Float16* __restrict__ S, uint16_t* __restrict__ P,
                                                    float* __restrict__ rden){
  __shared__ float red[8];
  const int row = blockIdx.x, tid = threadIdx.x;
  const f16x8* Sr = (const f16x8*)(S + (size_t)row * 4096);
  f16x8 h0 = Sr[tid], h1 = Sr[256 + tid];
  float v[16];
  float mx = -3.4e38f, sm = 0.f;
  #pragma unroll
  for (int e = 0; e < 8; ++e){ v[e] = (float)h0[e]; v[8 + e] = (float)h1[e]; }
  #pragma unroll
  for (int e = 0; e < 16; ++e){ mx = fmaxf(mx, v[e]); sm += v[e]; }
  for (int m = 32; m; m >>= 1){ mx = fmaxf(mx, __shfl_xor(mx, m)); sm += __shfl_xor(sm, m); }
  const int wid = tid >> 6;
  if ((tid & 63) == 0){ red[wid] = mx; red[4 + wid] = sm; }
  __syncthreads();
  mx = fmaxf(fmaxf(red[0], red[1]), fmaxf(red[2], red[3]));
  sm = red[4] + red[5] + red[6] + red[7];

  float bmu  = 1.2f * fmaxf(sm * (1.f / 4096.f), 0.f);
  float amax = 3.0f * (mx - bmu);                 // identical expression to per-element 'a' below
  float cut  = fminf(amax, 0.1f);

  float den = 0.f; uint16_t pv[16];
  #pragma unroll
  for (int e = 0; e < 16; ++e){
    float a  = 3.0f * (v[e] - bmu);
    float ev = (a >= cut) ? __expf((a - amax) * (1.f / 0.07f)) : 0.f;
    den += ev;
    pv[e] = f2bf(ev);
  }
  for (int m = 32; m; m >>= 1) den += __shfl_xor(den, m);
  __syncthreads();
  if ((tid & 63) == 0) red[wid] = den;
  __syncthreads();
  den = red[0] + red[1] + red[2] + red[3];
  if (tid == 0) rden[row] = 1.f / den;            // den >= 1 (argmax always kept)

  u16x8* Pr = (u16x8*)(P + (size_t)row * 4096);
  u16x8 o0, o1;
  #pragma unroll
  for (int e = 0; e < 8; ++e){ o0[e] = pv[e]; o1[e] = pv[8 + e]; }
  Pr[tid] = o0; Pr[256 + tid] = o1;
}

// ---------------- 8) z-partial reduction + rden scale + final layout ----------------
__global__ __launch_bounds__(256) void reduce_k(const float* __restrict__ Pz, const float* __restrict__ rden,
                                                float* __restrict__ out){
  const int t = blockIdx.x * 256 + threadIdx.x;   // float4 index, 786432 total
  const int row = t / 192, c4 = t % 192;          // 192 float4 per row
  const float4* p = (const float4*)Pz;
  const size_t i = (size_t)row * 192 + c4;
  float4 a = p[i], b = p[i + 786432], c = p[i + 2 * 786432], d = p[i + 3 * 786432];
  float rd = rden[row];
  float4 o;
  o.x = (a.x + b.x + c.x + d.x) * rd;
  o.y = (a.y + b.y + c.y + d.y) * rd;
  o.z = (a.z + b.z + c.z + d.z) * rd;
  o.w = (a.w + b.w + c.w + d.w) * rd;
  const int s = row & 1023, bb = row >> 10;       // out[s][b][c]
  ((float4*)out)[(size_t)s * 768 + bb * 192 + c4] = o;
}

// ---------------- launcher ----------------
extern "C" void kernel_launch(void* const* d_in, const int* in_sizes, int n_in,
                              void* d_out, int out_size, void* d_ws, size_t ws_size,
                              hipStream_t stream){
  (void)in_sizes; (void)n_in; (void)out_size; (void)ws_size;
  const float* ex   = (const float*)d_in[0];   // [4,1024,768] -> x[4096,768]
  const float* vext = (const float*)d_in[1];   // [48,24,24,64]
  const int*   idx  = (const int*)d_in[2];     // [4096]
  float* out = (float*)d_out;                  // [1024,4,768] fp32
  char* ws = (char*)d_ws;

  // ws layout (~90.3 MB). Region R is time-shared:
  //   phase A (gemm1/rowsoftmax): An(6.3M) | Bn(6.3M) | S16(33.5M)
  //   phase B (gemm2/reduce):     Pz partials 4 x 12.6M = 50.3M
  uint16_t* P    = (uint16_t*)(ws);                     // 33554432 B
  uint16_t* Vt   = (uint16_t*)(ws + 33554432);          //  6291456 B
  char*     R    = ws + 39845888;
  uint16_t* An   = (uint16_t*)(R);                      //  6291456 B
  uint16_t* Bn   = (uint16_t*)(R + 6291456);            //  6291456 B
  _Float16* S16  = (_Float16*)(R + 12582912);           // 33554432 B
  float*    Pz   = (float*)(R);                         // 50331648 B (aliases An/Bn/S16, phase B)
  float*    csum = (float*)(ws + 90177536);             //    98304 B
  float*    rden = (float*)(ws + 90275840);             //    16384 B
  int*      order= (int*)(ws + 90292224);               //    16384 B
  int*      cbase= (int*)(ws + 90308608);               //      256 B

  sort_k<<<1, 256, 0, stream>>>(idx, order, cbase);
  resize_k<<<dim3(48, 32), 256, 0, stream>>>(vext, Vt);
  csum_k<<<dim3(NCLU, 3), 256, 0, stream>>>(ex, order, cbase, csum);
  proxy_key_k<<<N_TOK, 256, 0, stream>>>(ex, idx, csum, An, Bn);
  // S = proxyn @ keyn^T   [4096 x 4096], K=768, fp16 out, XCD-swizzled
  gemm_bt_k<0><<<1024, 256, 0, stream>>>(An, Bn, 768, 768, 768, S16, nullptr);
  rowsoftmax_k<<<N_TOK, 256, 0, stream>>>(S16, P, rden);
  // out_partial[z] = softmax(S) @ v   [4096 x 768], K=4096, K-split x4, plain stores
  gemm_bt_k<1><<<768, 256, 0, stream>>>(P, Vt, 4096, 4096, 4096, nullptr, Pz);
  reduce_k<<<3072, 256, 0, stream>>>(Pz, rden, out);
}